// Round 5
// baseline (2308.721 us; speedup 1.0000x reference)
//
#include <hip/hip_runtime.h>
#include <hip/hip_fp16.h>

typedef _Float16 half8 __attribute__((ext_vector_type(8)));
typedef float floatx4 __attribute__((ext_vector_type(4)));

#define NW 8              // waves per fused block (512 threads)

// ---------------- QR: 3x3 Householder, LAPACK sgeqrf/sorgqr convention ----------------
__device__ inline void qr3_q(const double A[3][3], double Q[3][3]){
  double a[3][3];
#pragma unroll
  for (int r = 0; r < 3; r++)
#pragma unroll
    for (int c = 0; c < 3; c++) a[r][c] = A[r][c];

  double v1[3] = {1.0, 0.0, 0.0};
  double tau1 = 0.0;
  {
    double xn2 = a[1][0]*a[1][0] + a[2][0]*a[2][0];
    if (xn2 != 0.0){
      double alpha = a[0][0];
      double beta = -copysign(sqrt(alpha*alpha + xn2), alpha);
      tau1 = (beta - alpha) / beta;
      double inv = 1.0 / (alpha - beta);
      v1[1] = a[1][0] * inv;
      v1[2] = a[2][0] * inv;
#pragma unroll
      for (int c = 1; c < 3; c++){
        double w = a[0][c] + v1[1]*a[1][c] + v1[2]*a[2][c];
        double tw = tau1 * w;
        a[0][c] -= tw;
        a[1][c] -= tw * v1[1];
        a[2][c] -= tw * v1[2];
      }
    }
  }
  double tau2 = 0.0, v2 = 0.0;
  {
    double x2 = a[2][1];
    if (x2 != 0.0){
      double alpha = a[1][1];
      double beta = -copysign(sqrt(alpha*alpha + x2*x2), alpha);
      tau2 = (beta - alpha) / beta;
      v2 = x2 / (alpha - beta);
    }
  }
  double M[3][3] = {{1.0, 0.0, 0.0},
                    {0.0, 1.0 - tau2, -tau2*v2},
                    {0.0, -tau2*v2, 1.0 - tau2*v2*v2}};
#pragma unroll
  for (int c = 0; c < 3; c++){
    double w = v1[0]*M[0][c] + v1[1]*M[1][c] + v1[2]*M[2][c];
#pragma unroll
    for (int r = 0; r < 3; r++)
      Q[r][c] = M[r][c] - tau1 * v1[r] * w;
  }
}

// ---------------- SE(3) per-node epilogue from a local ds[13] ----------------
__device__ inline void se3_node_ds(int n, const float ds[13],
                                   const float* __restrict__ bc, const float* __restrict__ bR,
                                   const float* __restrict__ bt, const float* __restrict__ pos_in,
                                   float* __restrict__ pos_o, float* __restrict__ R_o,
                                   float* __restrict__ t_o, int layer){
  double A[3][3], Q[3][3];
#pragma unroll
  for (int r = 0; r < 3; r++)
#pragma unroll
    for (int c = 0; c < 3; c++)
      A[r][c] = (double)ds[1 + r*3 + c] + (double)bR[r*3 + c];
  qr3_q(A, Q);

  double pd = (double)ds[0] + (double)bc[0];
#pragma unroll
  for (int c = 0; c < 3; c++){
    double base = (layer == 0) ? (double)pos_in[n*3 + c] : (double)pos_o[n*3 + c];
    pos_o[n*3 + c] = (float)(base + pd);
  }

  if (layer == 0){
#pragma unroll
    for (int r = 0; r < 3; r++)
#pragma unroll
      for (int c = 0; c < 3; c++)
        R_o[n*9 + r*3 + c] = (float)Q[r][c];
  } else {
    double Rold[3][3];
#pragma unroll
    for (int r = 0; r < 3; r++)
#pragma unroll
      for (int c = 0; c < 3; c++)
        Rold[r][c] = (double)R_o[n*9 + r*3 + c];
#pragma unroll
    for (int r = 0; r < 3; r++)
#pragma unroll
      for (int c = 0; c < 3; c++){
        double s = Q[r][0]*Rold[0][c] + Q[r][1]*Rold[1][c] + Q[r][2]*Rold[2][c];
        R_o[n*9 + r*3 + c] = (float)s;
      }
  }
#pragma unroll
  for (int c = 0; c < 3; c++){
    double base = (layer == 0) ? 0.0 : (double)t_o[n*3 + c];
    t_o[n*3 + c] = (float)(base + (double)ds[10 + c] + (double)bt[c]);
  }
}

// ---------------- merged pre-kernel: x fp32->fp16 cvt + weight prep + cursor init ------
__launch_bounds__(256)
__global__ void k_pre(const float* __restrict__ x, _Float16* __restrict__ o, int N,
                      const float* __restrict__ Wl, const float* __restrict__ Wf,
                      const float* __restrict__ Wc, const float* __restrict__ WR,
                      const float* __restrict__ Wt, _Float16* __restrict__ wTx,
                      _Float16* __restrict__ wHd,
                      int* __restrict__ cursor, int nbuck, int cvtB){
  const int b = blockIdx.x;
  if (b < cvtB){
    int c = b*256 + threadIdx.x;       // half8 chunk id
    if (c >= (N+1)*16) return;
    int n = c >> 4;
    half8 h = {};
    if (n < N){
      const float* p = x + (size_t)c*8;
      float4 f0 = *(const float4*)p;
      float4 f1 = *(const float4*)(p + 4);
      h[0]=(_Float16)f0.x; h[1]=(_Float16)f0.y; h[2]=(_Float16)f0.z; h[3]=(_Float16)f0.w;
      h[4]=(_Float16)f1.x; h[5]=(_Float16)f1.y; h[6]=(_Float16)f1.z; h[7]=(_Float16)f1.w;
    }
    *(half8*)(o + (size_t)c*8) = h;
    return;
  }
  if (b == cvtB && threadIdx.x < nbuck) cursor[threadIdx.x] = 0;
  int t = (b - cvtB)*256 + threadIdx.x;
  if (t < 4*128*128){
    int l = t >> 14;
    int n = (t >> 7) & 127;
    int k = t & 127;
    const float* W = (l < 3) ? (Wl + (size_t)l*16384) : Wf;
    wTx[t] = (_Float16)W[k*128 + n];
  } else if (t < 4*128*128 + 3*16*128){
    int u = t - 4*128*128;
    int l = u >> 11;              // 16*128 = 2048 per slot
    int r = u & 2047;
    int n = r >> 7;
    int k = r & 127;
    float v = 0.f;
    if (n == 0)      v = Wc[(size_t)l*128 + k];
    else if (n < 10) v = WR[(size_t)l*1152 + k*9 + (n-1)];
    else if (n < 13) v = Wt[(size_t)l*384 + k*3 + (n-10)];
    wHd[u] = (_Float16)v;
  }
}

// ---------------- pass 1: bin edges into 512-node buckets ----------------
__launch_bounds__(256)
__global__ void k_bin(const int* __restrict__ src, const int* __restrict__ dst,
                      int E, int nbuck, int capB,
                      int* __restrict__ cursor, int* __restrict__ binned){
  __shared__ int cnt[128];
  __shared__ int segbase[128];
  const int tid = threadIdx.x;
  for (int t = tid; t < nbuck; t += 256) cnt[t] = 0;
  __syncthreads();
  const int e0 = blockIdx.x*4096 + tid;
  int pk[16], bk[16];
#pragma unroll
  for (int j = 0; j < 16; j++){
    int e = e0 + j*256;
    if (e < E){
      int d = dst[e], s = src[e];
      bk[j] = d >> 9;
      pk[j] = (s << 9) | (d & 511);
      atomicAdd(&cnt[bk[j]], 1);
    } else bk[j] = -1;
  }
  __syncthreads();
  for (int t = tid; t < nbuck; t += 256){
    int c = cnt[t];
    if (c > 0) segbase[t] = t*capB + atomicAdd(&cursor[t], c);
    cnt[t] = 0;
  }
  __syncthreads();
#pragma unroll
  for (int j = 0; j < 16; j++){
    if (bk[j] >= 0){
      int ord = atomicAdd(&cnt[bk[j]], 1);
      binned[segbase[bk[j]] + ord] = pk[j];
    }
  }
}

// ---------------- pass 2: per (256-node half-bucket, src-octile) edge lists ------------
// Segment (q in 0..1, o in 0..7) holds packed edges (src<<8)|dstLocal8, padded to mult of 16
// with (N<<8). qoff[bucket*17 + q*8 + o] = start offset within bucket csr region (17th = end).
// degI[node] = true degree.
__launch_bounds__(256)
__global__ void k_build(const int* __restrict__ binned, const int* __restrict__ cursor,
                        int N, int capB, int capC,
                        int* __restrict__ qoff, int* __restrict__ degI, int* __restrict__ csr){
  __shared__ int cqo[16];
  __shared__ int off[17];
  __shared__ int cur16[16];
  __shared__ int deg1[512];
  const int b = blockIdx.x, tid = threadIdx.x;
  if (tid < 16){ cqo[tid] = 0; cur16[tid] = 0; }
  for (int t = tid; t < 512; t += 256) deg1[t] = 0;
  __syncthreads();
  const int nE = cursor[b];
  const int gbase = b*capB;
  for (int i = tid; i < nE; i += 256){
    int v = binned[gbase + i];
    int dl = v & 511, s = v >> 9;
    int o = s >> 13; if (o > 7) o = 7;
    atomicAdd(&cqo[((dl >> 8) << 3) + o], 1);
    atomicAdd(&deg1[dl], 1);
  }
  __syncthreads();
  if (tid == 0){
    int acc = 0;
#pragma unroll
    for (int i = 0; i < 16; i++){ off[i] = acc; acc += (cqo[i] + 15) & ~15; }
    off[16] = acc;
  }
  __syncthreads();
  if (tid < 17) qoff[b*17 + tid] = off[tid];
  for (int t = tid; t < 512; t += 256) degI[b*512 + t] = deg1[t];
  const int csrb = b*capC;
  for (int i = tid; i < nE; i += 256){
    int v = binned[gbase + i];
    int dl = v & 511, s = v >> 9;
    int o = s >> 13; if (o > 7) o = 7;
    int qo = ((dl >> 8) << 3) + o;
    int pos = off[qo] + atomicAdd(&cur16[qo], 1);
    csr[csrb + pos] = (s << 8) | (dl & 255);
  }
  __syncthreads();
#pragma unroll
  for (int seg = 0; seg < 16; seg++){
    int cnt = cqo[seg], base = off[seg];
    int padlen = ((cnt + 15) & ~15) - cnt;
    for (int j = tid; j < padlen; j += 256) csr[csrb + base + cnt + j] = (N << 8);
  }
}

// ================= fused layer body (common gather + GEMM + staging) ===================
// Block: 256 nodes, 512 threads, ~136 KB LDS -> 1 block/CU. Gather sweeps 8 src-octiles in
// phase (barrier between) so each XCD's L2 holds one 2 MiB X slice at a time; edges are
// edge-parallel with ds_add_f32 into a fp32 LDS accumulator tile (16-deep load pipeline).
#define FUSED_COMMON_BODY \
  __shared__ __align__(16) unsigned char smem[256*132*4];   /* 135168 B */               \
  __shared__ float ldeg[256];                                                            \
  float*    lg32 = (float*)smem;                 /* [256][132] fp32 accum */             \
  _Float16* lg16 = (_Float16*)smem;              /* [256][136] fp16 out (reuse) */       \
  float*    lheads = (float*)(smem + 256*136*2); /* [256][16] */                         \
  const int tid  = threadIdx.x;                                                          \
  const int wave = tid >> 6;                                                             \
  const int lane = tid & 63;                                                             \
  const int quad = lane >> 4;                                                            \
  const int l16  = lane & 15;                                                            \
  const int rbase0 = blockIdx.x*256;                                                     \
  const int bucket = blockIdx.x >> 1, q = blockIdx.x & 1;                                \
  {                                                                                      \
    float4 z4 = {0.f, 0.f, 0.f, 0.f};                                                    \
    for (int t = tid; t < 256*132/4; t += 512) ((float4*)lg32)[t] = z4;                  \
    for (int t = tid; t < 256; t += 512) ldeg[t] = (float)degI[rbase0 + t];              \
  }                                                                                      \
  __syncthreads();                                                                       \
  {                                                                                      \
    const int csrb = bucket*capC;                                                        \
    const unsigned int* Xu = (const unsigned int*)Xin;                                   \
    const unsigned int* Pk = (const unsigned int*)csr;                                   \
    for (int o = 0; o < 8; o++){                                                         \
      int segb = qoff[bucket*17 + q*8 + o];                                              \
      int nume = qoff[bucket*17 + q*8 + o + 1] - segb;                                   \
      int e0 = (wave*nume/NW) & ~15;                                                     \
      int e1 = ((wave+1)*nume/NW) & ~15;                                                 \
      for (int eb = e0; eb < e1; eb += 64){                                              \
        unsigned int pk = Pk[csrb + segb + eb + lane];                                   \
        int cnt = e1 - eb; cnt = cnt > 64 ? 64 : cnt;                                    \
        for (int k = 0; k < cnt; k += 16){                                               \
          int sp[16]; unsigned int v[16];                                                \
          _Pragma("unroll")                                                              \
          for (int j = 0; j < 16; j++) sp[j] = __builtin_amdgcn_readlane((int)pk, k+j);  \
          _Pragma("unroll")                                                              \
          for (int j = 0; j < 16; j++) v[j] = Xu[(size_t)(sp[j] >> 8)*64 + lane];        \
          _Pragma("unroll")                                                              \
          for (int j = 0; j < 16; j++){                                                  \
            float2 f = __half22float2(*(__half2*)&v[j]);                                 \
            float* p = &lg32[(sp[j] & 255)*132 + 2*lane];                                \
            unsafeAtomicAdd(p, f.x);                                                     \
            unsafeAtomicAdd(p + 1, f.y);                                                 \
          }                                                                              \
        }                                                                                \
      }                                                                                  \
      __syncthreads();                                                                   \
    }                                                                                    \
  }                                                                                      \
  /* GEMM: wave -> row-frags {2w,2w+1} x 8 col-tiles */                                  \
  const int r0 = wave*32 + l16, r1 = r0 + 16;                                            \
  half8 af0[4], af1[4];                                                                  \
  _Pragma("unroll")                                                                      \
  for (int kc = 0; kc < 4; kc++){                                                        \
    int c0 = kc*32 + quad*8;                                                             \
    float4 fa = *(const float4*)&lg32[r0*132 + c0];                                      \
    float4 fb = *(const float4*)&lg32[r0*132 + c0 + 4];                                  \
    half8 a;                                                                             \
    a[0]=(_Float16)fa.x; a[1]=(_Float16)fa.y; a[2]=(_Float16)fa.z; a[3]=(_Float16)fa.w;  \
    a[4]=(_Float16)fb.x; a[5]=(_Float16)fb.y; a[6]=(_Float16)fb.z; a[7]=(_Float16)fb.w;  \
    af0[kc] = a;                                                                         \
    float4 fc = *(const float4*)&lg32[r1*132 + c0];                                      \
    float4 fd = *(const float4*)&lg32[r1*132 + c0 + 4];                                  \
    half8 b2;                                                                            \
    b2[0]=(_Float16)fc.x; b2[1]=(_Float16)fc.y; b2[2]=(_Float16)fc.z; b2[3]=(_Float16)fc.w;\
    b2[4]=(_Float16)fd.x; b2[5]=(_Float16)fd.y; b2[6]=(_Float16)fd.z; b2[7]=(_Float16)fd.w;\
    af1[kc] = b2;                                                                        \
  }                                                                                      \
  floatx4 acc0[8] = {}, acc1[8] = {};                                                    \
  _Pragma("unroll")                                                                      \
  for (int kc = 0; kc < 4; kc++)                                                         \
  {                                                                                      \
    _Pragma("unroll")                                                                    \
    for (int ct = 0; ct < 8; ct++){                                                      \
      half8 bf = *(const half8*)(Wmain + (size_t)((ct*16 + l16)*128 + kc*32 + quad*8));  \
      acc0[ct] = __builtin_amdgcn_mfma_f32_16x16x32_f16(af0[kc], bf, acc0[ct], 0, 0, 0); \
      acc1[ct] = __builtin_amdgcn_mfma_f32_16x16x32_f16(af1[kc], bf, acc1[ct], 0, 0, 0); \
    }                                                                                    \
  }                                                                                      \
  __syncthreads();  /* all lg32 reads done before fp16 overwrite */                      \
  _Pragma("unroll")                                                                      \
  for (int ct = 0; ct < 8; ct++){                                                        \
    int col = ct*16 + l16;                                                               \
    float bcol = bias[col];                                                              \
    _Pragma("unroll")                                                                    \
    for (int reg = 0; reg < 4; reg++){                                                   \
      int rl0 = wave*32 + quad*4 + reg;                                                  \
      lg16[rl0*136 + col] = (_Float16)(acc0[ct][reg] + bcol*ldeg[rl0]);                  \
      int rl1 = rl0 + 16;                                                                \
      lg16[rl1*136 + col] = (_Float16)(acc1[ct][reg] + bcol*ldeg[rl1]);                  \
    }                                                                                    \
  }                                                                                      \
  __syncthreads();

#define FUSED_HEADS_SE3_BODY \
  _Pragma("unroll")                                                                      \
  for (int rf = 0; rf < 2; rf++){                                                        \
    int t = wave*2 + rf;                                                                 \
    floatx4 hacc = {};                                                                   \
    _Pragma("unroll")                                                                    \
    for (int kc = 0; kc < 4; kc++){                                                      \
      half8 ha = *(const half8*)&lg16[(t*16 + l16)*136 + kc*32 + quad*8];                \
      half8 bfh = *(const half8*)(Whd + (size_t)l16*128 + kc*32 + quad*8);               \
      hacc = __builtin_amdgcn_mfma_f32_16x16x32_f16(ha, bfh, hacc, 0, 0, 0);             \
    }                                                                                    \
    _Pragma("unroll")                                                                    \
    for (int reg = 0; reg < 4; reg++)                                                    \
      lheads[(t*16 + quad*4 + reg)*16 + l16] = hacc[reg];                                \
  }                                                                                      \
  __syncthreads();                                                                       \
  if (tid < 256){                                                                        \
    int n = rbase0 + tid;                                                                \
    if (n < N){                                                                          \
      float dsv[13];                                                                     \
      _Pragma("unroll")                                                                  \
      for (int c = 0; c < 13; c++) dsv[c] = lheads[tid*16 + c];                          \
      se3_node_ds(n, dsv, bc, bR, bt, pos_in, pos_o, R_o, t_o, layer);                   \
    }                                                                                    \
  }

// ---------------- layers 0/1: store fp16 out, heads, SE(3) ----------------
__launch_bounds__(512)
__global__ void k_fused(const _Float16* __restrict__ Xin, const _Float16* __restrict__ Wmain,
                        const _Float16* __restrict__ Whd, const float* __restrict__ bias,
                        const int* __restrict__ csr, const int* __restrict__ qoff,
                        const int* __restrict__ degI, int capC,
                        _Float16* __restrict__ Out, int N, int layer,
                        const float* __restrict__ bc, const float* __restrict__ bR,
                        const float* __restrict__ bt, const float* __restrict__ pos_in,
                        float* __restrict__ pos_o, float* __restrict__ R_o,
                        float* __restrict__ t_o){
  FUSED_COMMON_BODY
  // coalesced fp16 out store (+ zero row N for padding reads)
#pragma unroll
  for (int i = 0; i < 8; i++){
    int idx8 = i*512 + tid;            // 4096 half8 chunks
    int row = idx8 >> 4, c8 = idx8 & 15;
    int gr = rbase0 + row;
    if (gr < N){
      *(half8*)(Out + (size_t)gr*128 + c8*8) = *(const half8*)&lg16[row*136 + c8*8];
    } else if (gr == N){
      half8 z = {};
      *(half8*)(Out + (size_t)gr*128 + c8*8) = z;
    }
  }
  FUSED_HEADS_SE3_BODY
}

// ---------------- layer 2: fused final GEMM z = out@Wf + bf (fp32), heads, SE(3) -------
__launch_bounds__(512)
__global__ void k_fused_fin(const _Float16* __restrict__ Xin, const _Float16* __restrict__ Wmain,
                        const _Float16* __restrict__ Whd, const float* __restrict__ bias,
                        const int* __restrict__ csr, const int* __restrict__ qoff,
                        const int* __restrict__ degI, int capC,
                        int N, int layer,
                        const float* __restrict__ bc, const float* __restrict__ bR,
                        const float* __restrict__ bt, const float* __restrict__ pos_in,
                        float* __restrict__ pos_o, float* __restrict__ R_o,
                        float* __restrict__ t_o,
                        const _Float16* __restrict__ Wfin, const float* __restrict__ bfin,
                        float* __restrict__ Zout){
  FUSED_COMMON_BODY
  // final GEMM from staged fp16 out
  {
    half8 zf0[4], zf1[4];
#pragma unroll
    for (int kc = 0; kc < 4; kc++){
      int c0 = kc*32 + quad*8;
      zf0[kc] = *(const half8*)&lg16[r0*136 + c0];
      zf1[kc] = *(const half8*)&lg16[r1*136 + c0];
    }
    floatx4 zacc0[8] = {}, zacc1[8] = {};
#pragma unroll
    for (int kc = 0; kc < 4; kc++)
#pragma unroll
      for (int ct = 0; ct < 8; ct++){
        half8 bf = *(const half8*)(Wfin + (size_t)((ct*16 + l16)*128 + kc*32 + quad*8));
        zacc0[ct] = __builtin_amdgcn_mfma_f32_16x16x32_f16(zf0[kc], bf, zacc0[ct], 0, 0, 0);
        zacc1[ct] = __builtin_amdgcn_mfma_f32_16x16x32_f16(zf1[kc], bf, zacc1[ct], 0, 0, 0);
      }
#pragma unroll
    for (int ct = 0; ct < 8; ct++){
      int col = ct*16 + l16;
      float b = bfin[col];
#pragma unroll
      for (int reg = 0; reg < 4; reg++){
        int gr0 = rbase0 + wave*32 + quad*4 + reg;
        if (gr0 < N) Zout[(size_t)gr0*128 + col] = zacc0[ct][reg] + b;
        int gr1 = gr0 + 16;
        if (gr1 < N) Zout[(size_t)gr1*128 + col] = zacc1[ct][reg] + b;
      }
    }
  }
  FUSED_HEADS_SE3_BODY
}

extern "C" void kernel_launch(void* const* d_in, const int* in_sizes, int n_in,
                              void* d_out, int out_size, void* d_ws, size_t ws_size,
                              hipStream_t stream){
  const float* x0  = (const float*)d_in[0];
  const float* pos = (const float*)d_in[1];
  const int*   ei  = (const int*)d_in[2];
  const float* Wl  = (const float*)d_in[3];
  const float* bl  = (const float*)d_in[4];
  const float* Wc  = (const float*)d_in[5];
  const float* bc  = (const float*)d_in[6];
  const float* WR  = (const float*)d_in[7];
  const float* bR  = (const float*)d_in[8];
  const float* Wt  = (const float*)d_in[9];
  const float* bt  = (const float*)d_in[10];
  const float* Wf  = (const float*)d_in[11];
  const float* bf  = (const float*)d_in[12];

  const int N = in_sizes[0] / 128;
  const int E = in_sizes[2] / 2;
  const int* srcp = ei;
  const int* dstp = ei + E;

  float* z_out = (float*)d_out;
  float* pos_o = z_out + (size_t)N*128;
  float* R_o   = pos_o + (size_t)N*3;
  float* t_o   = R_o   + (size_t)N*9;

  const int nbuck = (N + 511) >> 9;
  const int capB  = (((E + nbuck - 1)/nbuck)*5/4 + 256 + 63) & ~63;
  const int capC  = capB + 320;

  char* ws = (char*)d_ws;
  size_t off = 0;
  auto alloc = [&](size_t bytes)->char*{
    char* p = ws + off; off += (bytes + 511) & ~(size_t)511; return p;
  };
  _Float16* bufA = (_Float16*)alloc((size_t)(N+1)*128*2);   // x16 / out1
  _Float16* bufB = (_Float16*)alloc((size_t)(N+1)*128*2);   // out0 (out2 never stored)
  _Float16* wTx  = (_Float16*)alloc((size_t)4*128*128*2);
  _Float16* wHd  = (_Float16*)alloc((size_t)3*16*128*2);
  int*   qoff   = (int*)  alloc((size_t)nbuck*17*4);
  int*   degI   = (int*)  alloc((size_t)nbuck*512*4);
  int*   cursor = (int*)  alloc((size_t)nbuck*4);
  int*   binned = (int*)  alloc((size_t)nbuck*capB*4);
  int*   csr    = (int*)  alloc((size_t)nbuck*capC*4);

  const int cvtB = ((N+1)*16 + 255)/256;
  const int prep_total = 4*128*128 + 3*16*128;
  const int prepB = (prep_total + 255)/256;
  k_pre<<<dim3(cvtB + prepB), dim3(256), 0, stream>>>(
      x0, bufA, N, Wl, Wf, Wc, WR, Wt, wTx, wHd, cursor, nbuck, cvtB);
  k_bin  <<<dim3((E + 4095)/4096), dim3(256), 0, stream>>>(srcp, dstp, E, nbuck, capB, cursor, binned);
  k_build<<<dim3(nbuck), dim3(256), 0, stream>>>(binned, cursor, N, capB, capC, qoff, degI, csr);

  const int fused_blocks = nbuck*2;   // 256 rows/block; covers zero-pad row N

  // layer 0: bufA -> bufB
  k_fused<<<dim3(fused_blocks), dim3(512), 0, stream>>>(
      bufA, wTx, wHd, bl,
      csr, qoff, degI, capC, bufB, N, 0,
      bc, bR, bt, pos, pos_o, R_o, t_o);
  // layer 1: bufB -> bufA
  k_fused<<<dim3(fused_blocks), dim3(512), 0, stream>>>(
      bufB, wTx + (size_t)16384, wHd + (size_t)2048, bl + 128,
      csr, qoff, degI, capC, bufA, N, 1,
      bc + 1, bR + 9, bt + 3, pos, pos_o, R_o, t_o);
  // layer 2 (+ final GEMM): bufA -> z
  k_fused_fin<<<dim3(fused_blocks), dim3(512), 0, stream>>>(
      bufA, wTx + (size_t)2*16384, wHd + (size_t)2*2048, bl + 256,
      csr, qoff, degI, capC, N, 2,
      bc + 2, bR + 18, bt + 6, pos, pos_o, R_o, t_o,
      wTx + (size_t)3*16384, bf, z_out);
}

// Round 6
// 277.225 us; speedup vs baseline: 8.3280x; 8.3280x over previous
//
#include <hip/hip_runtime.h>
#include <hip/hip_fp16.h>

typedef _Float16 half8 __attribute__((ext_vector_type(8)));
typedef float floatx4 __attribute__((ext_vector_type(4)));

#define OSH 13            // src-octile shift for csr ordering (locality in gather)

// ---------------- QR: 3x3 Householder, LAPACK sgeqrf/sorgqr convention ----------------
__device__ inline void qr3_q(const double A[3][3], double Q[3][3]){
  double a[3][3];
#pragma unroll
  for (int r = 0; r < 3; r++)
#pragma unroll
    for (int c = 0; c < 3; c++) a[r][c] = A[r][c];

  double v1[3] = {1.0, 0.0, 0.0};
  double tau1 = 0.0;
  {
    double xn2 = a[1][0]*a[1][0] + a[2][0]*a[2][0];
    if (xn2 != 0.0){
      double alpha = a[0][0];
      double beta = -copysign(sqrt(alpha*alpha + xn2), alpha);
      tau1 = (beta - alpha) / beta;
      double inv = 1.0 / (alpha - beta);
      v1[1] = a[1][0] * inv;
      v1[2] = a[2][0] * inv;
#pragma unroll
      for (int c = 1; c < 3; c++){
        double w = a[0][c] + v1[1]*a[1][c] + v1[2]*a[2][c];
        double tw = tau1 * w;
        a[0][c] -= tw;
        a[1][c] -= tw * v1[1];
        a[2][c] -= tw * v1[2];
      }
    }
  }
  double tau2 = 0.0, v2 = 0.0;
  {
    double x2 = a[2][1];
    if (x2 != 0.0){
      double alpha = a[1][1];
      double beta = -copysign(sqrt(alpha*alpha + x2*x2), alpha);
      tau2 = (beta - alpha) / beta;
      v2 = x2 / (alpha - beta);
    }
  }
  double M[3][3] = {{1.0, 0.0, 0.0},
                    {0.0, 1.0 - tau2, -tau2*v2},
                    {0.0, -tau2*v2, 1.0 - tau2*v2*v2}};
#pragma unroll
  for (int c = 0; c < 3; c++){
    double w = v1[0]*M[0][c] + v1[1]*M[1][c] + v1[2]*M[2][c];
#pragma unroll
    for (int r = 0; r < 3; r++)
      Q[r][c] = M[r][c] - tau1 * v1[r] * w;
  }
}

// ---------------- SE(3) per-node epilogue from a local ds[13] ----------------
__device__ inline void se3_node_ds(int n, const float ds[13],
                                   const float* __restrict__ bc, const float* __restrict__ bR,
                                   const float* __restrict__ bt, const float* __restrict__ pos_in,
                                   float* __restrict__ pos_o, float* __restrict__ R_o,
                                   float* __restrict__ t_o, int layer){
  double A[3][3], Q[3][3];
#pragma unroll
  for (int r = 0; r < 3; r++)
#pragma unroll
    for (int c = 0; c < 3; c++)
      A[r][c] = (double)ds[1 + r*3 + c] + (double)bR[r*3 + c];
  qr3_q(A, Q);

  double pd = (double)ds[0] + (double)bc[0];
#pragma unroll
  for (int c = 0; c < 3; c++){
    double base = (layer == 0) ? (double)pos_in[n*3 + c] : (double)pos_o[n*3 + c];
    pos_o[n*3 + c] = (float)(base + pd);
  }

  if (layer == 0){
#pragma unroll
    for (int r = 0; r < 3; r++)
#pragma unroll
      for (int c = 0; c < 3; c++)
        R_o[n*9 + r*3 + c] = (float)Q[r][c];
  } else {
    double Rold[3][3];
#pragma unroll
    for (int r = 0; r < 3; r++)
#pragma unroll
      for (int c = 0; c < 3; c++)
        Rold[r][c] = (double)R_o[n*9 + r*3 + c];
#pragma unroll
    for (int r = 0; r < 3; r++)
#pragma unroll
      for (int c = 0; c < 3; c++){
        double s = Q[r][0]*Rold[0][c] + Q[r][1]*Rold[1][c] + Q[r][2]*Rold[2][c];
        R_o[n*9 + r*3 + c] = (float)s;
      }
  }
#pragma unroll
  for (int c = 0; c < 3; c++){
    double base = (layer == 0) ? 0.0 : (double)t_o[n*3 + c];
    t_o[n*3 + c] = (float)(base + (double)ds[10 + c] + (double)bt[c]);
  }
}

// ---------------- merged pre-kernel: x fp32->fp16 cvt + weight prep + cursor init ------
// blocks [0, cvtB): cvt (row N zeroed). blocks [cvtB, ...): weight prep.
// wTx: 4 slots x 128 cols x 128 k (main W, B-frag layout [col][k])
// wHd: 3 slots x 16 cols x 128 k (head W of layer l in slot l; cols 13-15 zero)
__launch_bounds__(256)
__global__ void k_pre(const float* __restrict__ x, _Float16* __restrict__ o, int N,
                      const float* __restrict__ Wl, const float* __restrict__ Wf,
                      const float* __restrict__ Wc, const float* __restrict__ WR,
                      const float* __restrict__ Wt, _Float16* __restrict__ wTx,
                      _Float16* __restrict__ wHd,
                      int* __restrict__ cursor, int nbuck, int cvtB){
  const int b = blockIdx.x;
  if (b < cvtB){
    int c = b*256 + threadIdx.x;       // half8 chunk id
    if (c >= (N+1)*16) return;
    int n = c >> 4;
    half8 h = {};
    if (n < N){
      const float* p = x + (size_t)c*8;
      float4 f0 = *(const float4*)p;
      float4 f1 = *(const float4*)(p + 4);
      h[0]=(_Float16)f0.x; h[1]=(_Float16)f0.y; h[2]=(_Float16)f0.z; h[3]=(_Float16)f0.w;
      h[4]=(_Float16)f1.x; h[5]=(_Float16)f1.y; h[6]=(_Float16)f1.z; h[7]=(_Float16)f1.w;
    }
    *(half8*)(o + (size_t)c*8) = h;
    return;
  }
  if (b == cvtB && threadIdx.x < nbuck) cursor[threadIdx.x] = 0;
  int t = (b - cvtB)*256 + threadIdx.x;
  if (t < 4*128*128){
    int l = t >> 14;
    int n = (t >> 7) & 127;
    int k = t & 127;
    const float* W = (l < 3) ? (Wl + (size_t)l*16384) : Wf;
    wTx[t] = (_Float16)W[k*128 + n];
  } else if (t < 4*128*128 + 3*16*128){
    int u = t - 4*128*128;
    int l = u >> 11;              // 16*128 = 2048 per slot
    int r = u & 2047;
    int n = r >> 7;
    int k = r & 127;
    float v = 0.f;
    if (n == 0)      v = Wc[(size_t)l*128 + k];
    else if (n < 10) v = WR[(size_t)l*1152 + k*9 + (n-1)];
    else if (n < 13) v = Wt[(size_t)l*384 + k*3 + (n-10)];
    wHd[u] = (_Float16)v;
  }
}

// ---------------- pass 1: bin edges into 512-node buckets ----------------
__launch_bounds__(256)
__global__ void k_bin(const int* __restrict__ src, const int* __restrict__ dst,
                      int E, int nbuck, int capB,
                      int* __restrict__ cursor, int* __restrict__ binned){
  __shared__ int cnt[128];
  __shared__ int segbase[128];
  const int tid = threadIdx.x;
  for (int t = tid; t < nbuck; t += 256) cnt[t] = 0;
  __syncthreads();
  const int e0 = blockIdx.x*4096 + tid;
  int pk[16], bk[16];
#pragma unroll
  for (int j = 0; j < 16; j++){
    int e = e0 + j*256;
    if (e < E){
      int d = dst[e], s = src[e];
      bk[j] = d >> 9;
      pk[j] = (s << 9) | (d & 511);
      atomicAdd(&cnt[bk[j]], 1);
    } else bk[j] = -1;
  }
  __syncthreads();
  for (int t = tid; t < nbuck; t += 256){
    int c = cnt[t];
    if (c > 0) segbase[t] = t*capB + atomicAdd(&cursor[t], c);
    cnt[t] = 0;
  }
  __syncthreads();
#pragma unroll
  for (int j = 0; j < 16; j++){
    if (bk[j] >= 0){
      int ord = atomicAdd(&cnt[bk[j]], 1);
      binned[segbase[bk[j]] + ord] = pk[j];
    }
  }
}

// ---------------- pass 2: per-bucket CSR, src-octile-ordered neighbor lists ----------------
// sd[n] = (csr_start, (true_deg << 16) | padded_deg)
__launch_bounds__(256)
__global__ void k_build(const int* __restrict__ binned, const int* __restrict__ cursor,
                        int N, int capB, int capC,
                        int2* __restrict__ sd, int* __restrict__ csr){
  __shared__ int deg2[512*8];
  __shared__ int lst2[512*8];
  __shared__ int cnt2[512*8];
  __shared__ int scn[256];
  const int b = blockIdx.x, tid = threadIdx.x;
  for (int t = tid; t < 512*8; t += 256){ deg2[t] = 0; cnt2[t] = 0; }
  __syncthreads();
  const int nE = cursor[b];
  const int gbase = b*capB;
  for (int i = tid; i < nE; i += 256){
    int v = binned[gbase + i];
    int o = v >> (9 + OSH);
    if (o > 7) o = 7;
    atomicAdd(&deg2[((v & 511) << 3) + o], 1);
  }
  __syncthreads();
  int d0 = 0, d1 = 0;
#pragma unroll
  for (int o = 0; o < 8; o++){ d0 += deg2[((2*tid) << 3) + o]; d1 += deg2[((2*tid+1) << 3) + o]; }
  const int p0 = (d0+7)&~7, p1 = (d1+7)&~7;
  scn[tid] = p0 + p1;
  __syncthreads();
#pragma unroll
  for (int off = 1; off < 256; off <<= 1){
    int add = (tid >= off) ? scn[tid-off] : 0;
    __syncthreads();
    scn[tid] += add;
    __syncthreads();
  }
  const int ex = scn[tid] - (p0 + p1);
  const int csrb = b*capC;
  {
    int off0 = ex;
#pragma unroll
    for (int o = 0; o < 8; o++){ lst2[((2*tid) << 3) + o] = off0; off0 += deg2[((2*tid) << 3) + o]; }
    int off1 = ex + p0;
#pragma unroll
    for (int o = 0; o < 8; o++){ lst2[((2*tid+1) << 3) + o] = off1; off1 += deg2[((2*tid+1) << 3) + o]; }
  }
  const int n0 = b*512 + 2*tid, n1 = n0 + 1;
  if (n0 < N) sd[n0] = make_int2(csrb + ex, (d0 << 16) | p0);
  if (n1 < N) sd[n1] = make_int2(csrb + ex + p0, (d1 << 16) | p1);
  __syncthreads();
  for (int i = tid; i < nE; i += 256){
    int v = binned[gbase + i];
    int dl = v & 511, s = v >> 9;
    int o = s >> OSH; if (o > 7) o = 7;
    int ord = atomicAdd(&cnt2[(dl << 3) + o], 1);
    csr[csrb + lst2[(dl << 3) + o] + ord] = s;
  }
  for (int j = d0; j < p0; j++) csr[csrb + ex + j] = N;
  for (int j = d1; j < p1; j++) csr[csrb + ex + p0 + j] = N;
}

// ---------------- fused layer kernel (layers 0/1): out = (A x) W + deg*b ---------------
// Per block: 64 nodes, 256 threads (R1 geometry — best measured).
// Phase 1: each wave gather-aggregates 16 rows of A*x into LDS (fp16).
// Phase 2: 64x128x128 MFMA GEMM (A from LDS, B=wTx), deg-scaled bias, stage out to LDS.
// Phase 3a: coalesced global store of out (+ zero row N).
// Phase 3b: 64x16x128 head MFMA from LDS. Phase 4: SE(3) epilogue.
__launch_bounds__(256)
__global__ void k_fused(const _Float16* __restrict__ Xin,     // (N+1) rows fp16
                        const _Float16* __restrict__ Wmain,   // 128x128 [col][k]
                        const _Float16* __restrict__ Whd,     // 16x128  [col][k]
                        const float* __restrict__ bias,       // bl[layer] (128)
                        const int* __restrict__ csr, const int2* __restrict__ sd,
                        _Float16* __restrict__ Out,           // (N+1) rows fp16
                        int N, int layer,
                        const float* __restrict__ bc, const float* __restrict__ bR,
                        const float* __restrict__ bt, const float* __restrict__ pos_in,
                        float* __restrict__ pos_o, float* __restrict__ R_o,
                        float* __restrict__ t_o){
  __shared__ __align__(16) _Float16 lg[64][136];   // gather tile, reused for out staging
  __shared__ __align__(16) float lheads[64*16];
  __shared__ float ldeg[64];

  const int tid  = threadIdx.x;
  const int wave = tid >> 6;
  const int lane = tid & 63;
  const int quad = lane >> 4;
  const int l16  = lane & 15;
  const int rbase0 = blockIdx.x*64;

  // ---- phase 1: gather-aggregate (wave w -> local rows w*16 .. w*16+15) ----
  {
    const int nbase = rbase0 + wave*16;
    int nn = nbase + (lane & 15);
    int2 sv = (nn < N) ? sd[nn] : make_int2(0, 0);
    const unsigned int* Xu = (const unsigned int*)Xin;
    for (int i = 0; i < 16; i++){
      int s0    = __builtin_amdgcn_readlane(sv.x, i);
      int dpack = __builtin_amdgcn_readlane(sv.y, i);
      int degp  = dpack & 0xffff;
      if (lane == 0) ldeg[wave*16 + i] = (float)(dpack >> 16);
      float acc0 = 0.f, acc1 = 0.f;
      for (int base = 0; base < degp; base += 64){
        int myidx = csr[s0 + base + lane];          // one coalesced load covers 64 edges
        int m = degp - base; m = (m < 64) ? m : 64; // multiple of 8
        for (int k = 0; k < m; k += 8){
          unsigned int v[8];
#pragma unroll
          for (int j = 0; j < 8; j++){
            int idx = __builtin_amdgcn_readlane(myidx, k + j);   // SGPR row index
            v[j] = Xu[(size_t)idx*64 + lane];
          }
#pragma unroll
          for (int j = 0; j < 8; j++){
            float2 f = __half22float2(*(__half2*)&v[j]);
            acc0 += f.x; acc1 += f.y;
          }
        }
      }
      __half2 ho = __floats2half2_rn(acc0, acc1);
      ((unsigned int*)&lg[wave*16 + i][0])[lane] = *(unsigned int*)&ho;
    }
  }
  __syncthreads();

  // ---- phase 2: MFMA GEMM. waves 0,1: cols 0-63; waves 2,3: cols 64-127 ----
  const int cthi = wave >> 1;
  half8 af[4][2];
#pragma unroll
  for (int kc = 0; kc < 4; kc++)
#pragma unroll
    for (int rt = 0; rt < 2; rt++){
      int rl = (wave & 1)*32 + rt*16 + l16;
      af[kc][rt] = *(const half8*)&lg[rl][kc*32 + quad*8];
    }
  __syncthreads();   // all lg reads done before out staging overwrites it

  floatx4 acc[2][4] = {};
#pragma unroll
  for (int kc = 0; kc < 4; kc++)
#pragma unroll
    for (int ct = 0; ct < 4; ct++){
      half8 bf = *(const half8*)(Wmain + (size_t)((cthi*4 + ct)*16 + l16)*128 + kc*32 + quad*8);
      acc[0][ct] = __builtin_amdgcn_mfma_f32_16x16x32_f16(af[kc][0], bf, acc[0][ct], 0, 0, 0);
      acc[1][ct] = __builtin_amdgcn_mfma_f32_16x16x32_f16(af[kc][1], bf, acc[1][ct], 0, 0, 0);
    }

  // ---- stage out to LDS (deg-scaled bias: reference sums (x W + b) over neighbors) ----
#pragma unroll
  for (int rt = 0; rt < 2; rt++){
    float dgv[4];
#pragma unroll
    for (int reg = 0; reg < 4; reg++)
      dgv[reg] = ldeg[(wave & 1)*32 + rt*16 + quad*4 + reg];
#pragma unroll
    for (int ct = 0; ct < 4; ct++){
      int col = (cthi*4 + ct)*16 + l16;
      float b = bias[col];
#pragma unroll
      for (int reg = 0; reg < 4; reg++){
        int rl = (wave & 1)*32 + rt*16 + quad*4 + reg;
        lg[rl][col] = (_Float16)(acc[rt][ct][reg] + b*dgv[reg]);
      }
    }
  }
  __syncthreads();

  // ---- phase 3a: coalesced global store (half8 chunks), zero row N for csr padding ----
#pragma unroll
  for (int i = 0; i < 4; i++){
    int idx8 = i*256 + tid;            // 1024 half8 chunks
    int row = idx8 >> 4, c8 = idx8 & 15;
    int gr = rbase0 + row;
    if (gr < N){
      *(half8*)(Out + (size_t)gr*128 + c8*8) = *(const half8*)&lg[row][c8*8];
    } else if (gr == N){
      half8 z = {};
      *(half8*)(Out + (size_t)gr*128 + c8*8) = z;
    }
  }

  // ---- phase 3b: head GEMM out_l @ Whd (wave w -> row-tile w) ----
  {
    floatx4 hacc = {};
#pragma unroll
    for (int kc = 0; kc < 4; kc++){
      half8 ha = *(const half8*)&lg[wave*16 + l16][kc*32 + quad*8];
      half8 bf = *(const half8*)(Whd + (size_t)l16*128 + kc*32 + quad*8);
      hacc = __builtin_amdgcn_mfma_f32_16x16x32_f16(ha, bf, hacc, 0, 0, 0);
    }
#pragma unroll
    for (int reg = 0; reg < 4; reg++)
      lheads[(wave*16 + quad*4 + reg)*16 + l16] = hacc[reg];
  }
  __syncthreads();

  // ---- phase 4: SE(3) epilogue for this layer ----
  if (tid < 64){
    int n = rbase0 + tid;
    if (n < N){
      float ds[13];
#pragma unroll
      for (int c = 0; c < 13; c++) ds[c] = lheads[tid*16 + c];
      se3_node_ds(n, ds, bc, bR, bt, pos_in, pos_o, R_o, t_o, layer);
    }
  }
}

// ---------------- layer-2 kernel: fused final GEMM z = out@Wf + bf (fp32) ---------------
// Same body as k_fused but out never hits global; z computed in-block and stored fp32.
__launch_bounds__(256)
__global__ void k_fused_fin(const _Float16* __restrict__ Xin,
                        const _Float16* __restrict__ Wmain,
                        const _Float16* __restrict__ Whd,
                        const float* __restrict__ bias,
                        const int* __restrict__ csr, const int2* __restrict__ sd,
                        int N, int layer,
                        const float* __restrict__ bc, const float* __restrict__ bR,
                        const float* __restrict__ bt, const float* __restrict__ pos_in,
                        float* __restrict__ pos_o, float* __restrict__ R_o,
                        float* __restrict__ t_o,
                        const _Float16* __restrict__ Wfin,
                        const float* __restrict__ bfin,
                        float* __restrict__ Zout){
  __shared__ __align__(16) _Float16 lg[64][136];
  __shared__ __align__(16) float lheads[64*16];
  __shared__ float ldeg[64];

  const int tid  = threadIdx.x;
  const int wave = tid >> 6;
  const int lane = tid & 63;
  const int quad = lane >> 4;
  const int l16  = lane & 15;
  const int rbase0 = blockIdx.x*64;

  // ---- phase 1: gather-aggregate ----
  {
    const int nbase = rbase0 + wave*16;
    int nn = nbase + (lane & 15);
    int2 sv = (nn < N) ? sd[nn] : make_int2(0, 0);
    const unsigned int* Xu = (const unsigned int*)Xin;
    for (int i = 0; i < 16; i++){
      int s0    = __builtin_amdgcn_readlane(sv.x, i);
      int dpack = __builtin_amdgcn_readlane(sv.y, i);
      int degp  = dpack & 0xffff;
      if (lane == 0) ldeg[wave*16 + i] = (float)(dpack >> 16);
      float acc0 = 0.f, acc1 = 0.f;
      for (int base = 0; base < degp; base += 64){
        int myidx = csr[s0 + base + lane];
        int m = degp - base; m = (m < 64) ? m : 64;
        for (int k = 0; k < m; k += 8){
          unsigned int v[8];
#pragma unroll
          for (int j = 0; j < 8; j++){
            int idx = __builtin_amdgcn_readlane(myidx, k + j);
            v[j] = Xu[(size_t)idx*64 + lane];
          }
#pragma unroll
          for (int j = 0; j < 8; j++){
            float2 f = __half22float2(*(__half2*)&v[j]);
            acc0 += f.x; acc1 += f.y;
          }
        }
      }
      __half2 ho = __floats2half2_rn(acc0, acc1);
      ((unsigned int*)&lg[wave*16 + i][0])[lane] = *(unsigned int*)&ho;
    }
  }
  __syncthreads();

  // ---- phase 2: MFMA GEMM ----
  const int cthi = wave >> 1;
  half8 af[4][2];
#pragma unroll
  for (int kc = 0; kc < 4; kc++)
#pragma unroll
    for (int rt = 0; rt < 2; rt++){
      int rl = (wave & 1)*32 + rt*16 + l16;
      af[kc][rt] = *(const half8*)&lg[rl][kc*32 + quad*8];
    }
  __syncthreads();

  floatx4 acc[2][4] = {};
#pragma unroll
  for (int kc = 0; kc < 4; kc++)
#pragma unroll
    for (int ct = 0; ct < 4; ct++){
      half8 bf = *(const half8*)(Wmain + (size_t)((cthi*4 + ct)*16 + l16)*128 + kc*32 + quad*8);
      acc[0][ct] = __builtin_amdgcn_mfma_f32_16x16x32_f16(af[kc][0], bf, acc[0][ct], 0, 0, 0);
      acc[1][ct] = __builtin_amdgcn_mfma_f32_16x16x32_f16(af[kc][1], bf, acc[1][ct], 0, 0, 0);
    }

#pragma unroll
  for (int rt = 0; rt < 2; rt++){
    float dgv[4];
#pragma unroll
    for (int reg = 0; reg < 4; reg++)
      dgv[reg] = ldeg[(wave & 1)*32 + rt*16 + quad*4 + reg];
#pragma unroll
    for (int ct = 0; ct < 4; ct++){
      int col = (cthi*4 + ct)*16 + l16;
      float b = bias[col];
#pragma unroll
      for (int reg = 0; reg < 4; reg++){
        int rl = (wave & 1)*32 + rt*16 + quad*4 + reg;
        lg[rl][col] = (_Float16)(acc[rt][ct][reg] + b*dgv[reg]);
      }
    }
  }
  __syncthreads();

  // ---- phase 3a': fused final GEMM  z = out @ Wf + bf, direct fp32 store ----
  {
    half8 zf[4][2];
#pragma unroll
    for (int kc = 0; kc < 4; kc++)
#pragma unroll
      for (int rt = 0; rt < 2; rt++){
        int rl = (wave & 1)*32 + rt*16 + l16;
        zf[kc][rt] = *(const half8*)&lg[rl][kc*32 + quad*8];
      }
    floatx4 zacc[2][4] = {};
#pragma unroll
    for (int kc = 0; kc < 4; kc++)
#pragma unroll
      for (int ct = 0; ct < 4; ct++){
        half8 bf = *(const half8*)(Wfin + (size_t)((cthi*4 + ct)*16 + l16)*128 + kc*32 + quad*8);
        zacc[0][ct] = __builtin_amdgcn_mfma_f32_16x16x32_f16(zf[kc][0], bf, zacc[0][ct], 0, 0, 0);
        zacc[1][ct] = __builtin_amdgcn_mfma_f32_16x16x32_f16(zf[kc][1], bf, zacc[1][ct], 0, 0, 0);
      }
#pragma unroll
    for (int rt = 0; rt < 2; rt++)
#pragma unroll
      for (int ct = 0; ct < 4; ct++){
        int col = (cthi*4 + ct)*16 + l16;
        float b = bfin[col];
#pragma unroll
        for (int reg = 0; reg < 4; reg++){
          int gr = rbase0 + (wave & 1)*32 + rt*16 + quad*4 + reg;
          if (gr < N) Zout[(size_t)gr*128 + col] = zacc[rt][ct][reg] + b;
        }
      }
  }

  // ---- phase 3b: head GEMM ----
  {
    floatx4 hacc = {};
#pragma unroll
    for (int kc = 0; kc < 4; kc++){
      half8 ha = *(const half8*)&lg[wave*16 + l16][kc*32 + quad*8];
      half8 bf = *(const half8*)(Whd + (size_t)l16*128 + kc*32 + quad*8);
      hacc = __builtin_amdgcn_mfma_f32_16x16x32_f16(ha, bf, hacc, 0, 0, 0);
    }
#pragma unroll
    for (int reg = 0; reg < 4; reg++)
      lheads[(wave*16 + quad*4 + reg)*16 + l16] = hacc[reg];
  }
  __syncthreads();

  // ---- phase 4: SE(3) epilogue ----
  if (tid < 64){
    int n = rbase0 + tid;
    if (n < N){
      float ds[13];
#pragma unroll
      for (int c = 0; c < 13; c++) ds[c] = lheads[tid*16 + c];
      se3_node_ds(n, ds, bc, bR, bt, pos_in, pos_o, R_o, t_o, layer);
    }
  }
}

extern "C" void kernel_launch(void* const* d_in, const int* in_sizes, int n_in,
                              void* d_out, int out_size, void* d_ws, size_t ws_size,
                              hipStream_t stream){
  const float* x0  = (const float*)d_in[0];
  const float* pos = (const float*)d_in[1];
  const int*   ei  = (const int*)d_in[2];
  const float* Wl  = (const float*)d_in[3];
  const float* bl  = (const float*)d_in[4];
  const float* Wc  = (const float*)d_in[5];
  const float* bc  = (const float*)d_in[6];
  const float* WR  = (const float*)d_in[7];
  const float* bR  = (const float*)d_in[8];
  const float* Wt  = (const float*)d_in[9];
  const float* bt  = (const float*)d_in[10];
  const float* Wf  = (const float*)d_in[11];
  const float* bf  = (const float*)d_in[12];

  const int N = in_sizes[0] / 128;
  const int E = in_sizes[2] / 2;
  const int* srcp = ei;
  const int* dstp = ei + E;

  float* z_out = (float*)d_out;
  float* pos_o = z_out + (size_t)N*128;
  float* R_o   = pos_o + (size_t)N*3;
  float* t_o   = R_o   + (size_t)N*9;

  const int nbuck = (N + 511) >> 9;
  const int capB  = (((E + nbuck - 1)/nbuck)*5/4 + 256 + 63) & ~63;
  const int capC  = capB + 512*7;

  char* ws = (char*)d_ws;
  size_t off = 0;
  auto alloc = [&](size_t bytes)->char*{
    char* p = ws + off; off += (bytes + 511) & ~(size_t)511; return p;
  };
  _Float16* bufA = (_Float16*)alloc((size_t)(N+1)*128*2);   // x16 / out1
  _Float16* bufB = (_Float16*)alloc((size_t)(N+1)*128*2);   // out0 (out2 never stored)
  _Float16* wTx  = (_Float16*)alloc((size_t)4*128*128*2);
  _Float16* wHd  = (_Float16*)alloc((size_t)3*16*128*2);
  int2*  sd     = (int2*) alloc((size_t)N*8);
  int*   cursor = (int*)  alloc((size_t)nbuck*4);
  int*   binned = (int*)  alloc((size_t)nbuck*capB*4);
  int*   csr    = (int*)  alloc((size_t)nbuck*capC*4);

  const int cvtB = ((N+1)*16 + 255)/256;
  const int prep_total = 4*128*128 + 3*16*128;
  const int prepB = (prep_total + 255)/256;
  k_pre<<<dim3(cvtB + prepB), dim3(256), 0, stream>>>(
      x0, bufA, N, Wl, Wf, Wc, WR, Wt, wTx, wHd, cursor, nbuck, cvtB);
  k_bin   <<<dim3((E + 4095)/4096), dim3(256), 0, stream>>>(srcp, dstp, E, nbuck, capB, cursor, binned);
  k_build <<<dim3(nbuck), dim3(256), 0, stream>>>(binned, cursor, N, capB, capC, sd, csr);

  const int fused_blocks = (N + 64) >> 6;   // 64 rows/block; covers zero-pad row N

  // layer 0: bufA -> bufB
  k_fused<<<dim3(fused_blocks), dim3(256), 0, stream>>>(
      bufA, wTx, wHd, bl,
      csr, sd, bufB, N, 0,
      bc, bR, bt, pos, pos_o, R_o, t_o);
  // layer 1: bufB -> bufA
  k_fused<<<dim3(fused_blocks), dim3(256), 0, stream>>>(
      bufB, wTx + (size_t)16384, wHd + (size_t)2048, bl + 128,
      csr, sd, bufA, N, 1,
      bc + 1, bR + 9, bt + 3, pos, pos_o, R_o, t_o);
  // layer 2 (+ fused final GEMM): bufA -> z
  k_fused_fin<<<dim3(fused_blocks), dim3(256), 0, stream>>>(
      bufA, wTx + (size_t)2*16384, wHd + (size_t)2*2048, bl + 256,
      csr, sd, N, 2,
      bc + 2, bR + 18, bt + 6, pos, pos_o, R_o, t_o,
      wTx + (size_t)3*16384, bf, z_out);
}

// Round 7
// 267.908 us; speedup vs baseline: 8.6176x; 1.0348x over previous
//
#include <hip/hip_runtime.h>
#include <hip/hip_fp16.h>

typedef _Float16 half8 __attribute__((ext_vector_type(8)));
typedef float floatx4 __attribute__((ext_vector_type(4)));

#define OSH 13            // src-octile shift for csr ordering (locality in gather)
#define BN  128           // nodes per bucket (small buckets -> k_build parallelism)
#define BSH 7             // log2(BN)

// ---------------- QR: 3x3 Householder, LAPACK sgeqrf/sorgqr convention ----------------
__device__ inline void qr3_q(const double A[3][3], double Q[3][3]){
  double a[3][3];
#pragma unroll
  for (int r = 0; r < 3; r++)
#pragma unroll
    for (int c = 0; c < 3; c++) a[r][c] = A[r][c];

  double v1[3] = {1.0, 0.0, 0.0};
  double tau1 = 0.0;
  {
    double xn2 = a[1][0]*a[1][0] + a[2][0]*a[2][0];
    if (xn2 != 0.0){
      double alpha = a[0][0];
      double beta = -copysign(sqrt(alpha*alpha + xn2), alpha);
      tau1 = (beta - alpha) / beta;
      double inv = 1.0 / (alpha - beta);
      v1[1] = a[1][0] * inv;
      v1[2] = a[2][0] * inv;
#pragma unroll
      for (int c = 1; c < 3; c++){
        double w = a[0][c] + v1[1]*a[1][c] + v1[2]*a[2][c];
        double tw = tau1 * w;
        a[0][c] -= tw;
        a[1][c] -= tw * v1[1];
        a[2][c] -= tw * v1[2];
      }
    }
  }
  double tau2 = 0.0, v2 = 0.0;
  {
    double x2 = a[2][1];
    if (x2 != 0.0){
      double alpha = a[1][1];
      double beta = -copysign(sqrt(alpha*alpha + x2*x2), alpha);
      tau2 = (beta - alpha) / beta;
      v2 = x2 / (alpha - beta);
    }
  }
  double M[3][3] = {{1.0, 0.0, 0.0},
                    {0.0, 1.0 - tau2, -tau2*v2},
                    {0.0, -tau2*v2, 1.0 - tau2*v2*v2}};
#pragma unroll
  for (int c = 0; c < 3; c++){
    double w = v1[0]*M[0][c] + v1[1]*M[1][c] + v1[2]*M[2][c];
#pragma unroll
    for (int r = 0; r < 3; r++)
      Q[r][c] = M[r][c] - tau1 * v1[r] * w;
  }
}

// ---------------- SE(3) per-node epilogue from a local ds[13] ----------------
__device__ inline void se3_node_ds(int n, const float ds[13],
                                   const float* __restrict__ bc, const float* __restrict__ bR,
                                   const float* __restrict__ bt, const float* __restrict__ pos_in,
                                   float* __restrict__ pos_o, float* __restrict__ R_o,
                                   float* __restrict__ t_o, int layer){
  double A[3][3], Q[3][3];
#pragma unroll
  for (int r = 0; r < 3; r++)
#pragma unroll
    for (int c = 0; c < 3; c++)
      A[r][c] = (double)ds[1 + r*3 + c] + (double)bR[r*3 + c];
  qr3_q(A, Q);

  double pd = (double)ds[0] + (double)bc[0];
#pragma unroll
  for (int c = 0; c < 3; c++){
    double base = (layer == 0) ? (double)pos_in[n*3 + c] : (double)pos_o[n*3 + c];
    pos_o[n*3 + c] = (float)(base + pd);
  }

  if (layer == 0){
#pragma unroll
    for (int r = 0; r < 3; r++)
#pragma unroll
      for (int c = 0; c < 3; c++)
        R_o[n*9 + r*3 + c] = (float)Q[r][c];
  } else {
    double Rold[3][3];
#pragma unroll
    for (int r = 0; r < 3; r++)
#pragma unroll
      for (int c = 0; c < 3; c++)
        Rold[r][c] = (double)R_o[n*9 + r*3 + c];
#pragma unroll
    for (int r = 0; r < 3; r++)
#pragma unroll
      for (int c = 0; c < 3; c++){
        double s = Q[r][0]*Rold[0][c] + Q[r][1]*Rold[1][c] + Q[r][2]*Rold[2][c];
        R_o[n*9 + r*3 + c] = (float)s;
      }
  }
#pragma unroll
  for (int c = 0; c < 3; c++){
    double base = (layer == 0) ? 0.0 : (double)t_o[n*3 + c];
    t_o[n*3 + c] = (float)(base + (double)ds[10 + c] + (double)bt[c]);
  }
}

// ------------- merged pre-kernel: cvt | weight prep | edge binning (one dispatch) -------
// blocks [0, cvtB): x fp32->fp16 (row N zeroed)
// blocks [cvtB, cvtB+prepB): wTx (4 x 128x128 [col][k]) + wHd (3 x 16x128)
// blocks [cvtB+prepB, ...): bin edges into BN-node buckets (cursor pre-zeroed via memset)
__launch_bounds__(256)
__global__ void k_prebin(const float* __restrict__ x, _Float16* __restrict__ o, int N,
                         const float* __restrict__ Wl, const float* __restrict__ Wf,
                         const float* __restrict__ Wc, const float* __restrict__ WR,
                         const float* __restrict__ Wt, _Float16* __restrict__ wTx,
                         _Float16* __restrict__ wHd,
                         const int* __restrict__ src, const int* __restrict__ dst,
                         int E, int nbuck, int capB,
                         int* __restrict__ cursor, int* __restrict__ binned,
                         int cvtB, int prepB){
  __shared__ int cnt[512];
  __shared__ int segbase[512];
  const int b = blockIdx.x;
  const int tid = threadIdx.x;

  if (b < cvtB){
    int c = b*256 + tid;               // half8 chunk id
    if (c >= (N+1)*16) return;
    int n = c >> 4;
    half8 h = {};
    if (n < N){
      const float* p = x + (size_t)c*8;
      float4 f0 = *(const float4*)p;
      float4 f1 = *(const float4*)(p + 4);
      h[0]=(_Float16)f0.x; h[1]=(_Float16)f0.y; h[2]=(_Float16)f0.z; h[3]=(_Float16)f0.w;
      h[4]=(_Float16)f1.x; h[5]=(_Float16)f1.y; h[6]=(_Float16)f1.z; h[7]=(_Float16)f1.w;
    }
    *(half8*)(o + (size_t)c*8) = h;
    return;
  }
  if (b < cvtB + prepB){
    int t = (b - cvtB)*256 + tid;
    if (t < 4*128*128){
      int l = t >> 14;
      int n = (t >> 7) & 127;
      int k = t & 127;
      const float* W = (l < 3) ? (Wl + (size_t)l*16384) : Wf;
      wTx[t] = (_Float16)W[k*128 + n];
    } else if (t < 4*128*128 + 3*16*128){
      int u = t - 4*128*128;
      int l = u >> 11;              // 16*128 = 2048 per slot
      int r = u & 2047;
      int n = r >> 7;
      int k = r & 127;
      float v = 0.f;
      if (n == 0)      v = Wc[(size_t)l*128 + k];
      else if (n < 10) v = WR[(size_t)l*1152 + k*9 + (n-1)];
      else if (n < 13) v = Wt[(size_t)l*384 + k*3 + (n-10)];
      wHd[u] = (_Float16)v;
    }
    return;
  }

  // ---- binning part ----
  const int bb = b - cvtB - prepB;
  for (int t = tid; t < nbuck; t += 256) cnt[t] = 0;
  __syncthreads();
  const int e0 = bb*4096 + tid;
  int pk[16], bk[16];
#pragma unroll
  for (int j = 0; j < 16; j++){
    int e = e0 + j*256;
    if (e < E){
      int d = dst[e], s = src[e];
      bk[j] = d >> BSH;
      pk[j] = (s << BSH) | (d & (BN-1));
      atomicAdd(&cnt[bk[j]], 1);
    } else bk[j] = -1;
  }
  __syncthreads();
  for (int t = tid; t < nbuck; t += 256){
    int c = cnt[t];
    if (c > 0) segbase[t] = t*capB + atomicAdd(&cursor[t], c);
    cnt[t] = 0;
  }
  __syncthreads();
#pragma unroll
  for (int j = 0; j < 16; j++){
    if (bk[j] >= 0){
      int ord = atomicAdd(&cnt[bk[j]], 1);
      binned[segbase[bk[j]] + ord] = pk[j];
    }
  }
}

// ---------------- pass 2: per-bucket CSR (BN=128 nodes), src-octile-ordered lists -------
// sd[n] = (csr_start, (true_deg << 16) | padded_deg)
__launch_bounds__(256)
__global__ void k_build(const int* __restrict__ binned, const int* __restrict__ cursor,
                        int N, int capB, int capC,
                        int2* __restrict__ sd, int* __restrict__ csr){
  __shared__ int deg2[BN*8];
  __shared__ int lst2[BN*8];
  __shared__ int cnt2[BN*8];
  __shared__ int scn[BN];
  const int b = blockIdx.x, tid = threadIdx.x;
  for (int t = tid; t < BN*8; t += 256){ deg2[t] = 0; cnt2[t] = 0; }
  __syncthreads();
  const int nE = cursor[b];
  const int gbase = b*capB;
  for (int i = tid; i < nE; i += 256){
    int v = binned[gbase + i];
    int s = v >> BSH;
    int o = s >> OSH; if (o > 7) o = 7;
    atomicAdd(&deg2[((v & (BN-1)) << 3) + o], 1);
  }
  __syncthreads();
  int d0 = 0, p0 = 0;
  if (tid < BN){
#pragma unroll
    for (int o = 0; o < 8; o++) d0 += deg2[(tid << 3) + o];
    p0 = (d0+7)&~7;
    scn[tid] = p0;
  }
  __syncthreads();
#pragma unroll
  for (int off = 1; off < BN; off <<= 1){
    int add = 0;
    if (tid < BN && tid >= off) add = scn[tid-off];
    __syncthreads();
    if (tid < BN) scn[tid] += add;
    __syncthreads();
  }
  const int csrb = b*capC;
  int ex = 0;
  if (tid < BN){
    ex = scn[tid] - p0;
    int off0 = ex;
#pragma unroll
    for (int o = 0; o < 8; o++){ lst2[(tid << 3) + o] = off0; off0 += deg2[(tid << 3) + o]; }
    int n0 = b*BN + tid;
    if (n0 < N) sd[n0] = make_int2(csrb + ex, (d0 << 16) | p0);
  }
  __syncthreads();
  for (int i = tid; i < nE; i += 256){
    int v = binned[gbase + i];
    int dl = v & (BN-1), s = v >> BSH;
    int o = s >> OSH; if (o > 7) o = 7;
    int ord = atomicAdd(&cnt2[(dl << 3) + o], 1);
    csr[csrb + lst2[(dl << 3) + o] + ord] = s;
  }
  __syncthreads();
  if (tid < BN){
    for (int j = d0; j < p0; j++) csr[csrb + ex + j] = N;
  }
}

// ---------------- fused layer kernel (layers 0/1): out = (A x) W + deg*b ---------------
// Per block: 64 nodes, 256 threads.
// Phase 1: each wave gather-aggregates 16 rows of A*x into LDS (fp16).
// Phase 2: 64x128x128 MFMA GEMM (A from LDS, B=wTx), deg-scaled bias, stage out to LDS.
// Phase 3a: coalesced global store of out (+ zero row N).
// Phase 3b: 64x16x128 head MFMA from LDS. Phase 4: SE(3) epilogue.
__launch_bounds__(256)
__global__ void k_fused(const _Float16* __restrict__ Xin,     // (N+1) rows fp16
                        const _Float16* __restrict__ Wmain,   // 128x128 [col][k]
                        const _Float16* __restrict__ Whd,     // 16x128  [col][k]
                        const float* __restrict__ bias,       // bl[layer] (128)
                        const int* __restrict__ csr, const int2* __restrict__ sd,
                        _Float16* __restrict__ Out,           // (N+1) rows fp16
                        int N, int layer,
                        const float* __restrict__ bc, const float* __restrict__ bR,
                        const float* __restrict__ bt, const float* __restrict__ pos_in,
                        float* __restrict__ pos_o, float* __restrict__ R_o,
                        float* __restrict__ t_o){
  __shared__ __align__(16) _Float16 lg[64][136];   // gather tile, reused for out staging
  __shared__ __align__(16) float lheads[64*16];
  __shared__ float ldeg[64];

  const int tid  = threadIdx.x;
  const int wave = tid >> 6;
  const int lane = tid & 63;
  const int quad = lane >> 4;
  const int l16  = lane & 15;
  const int rbase0 = blockIdx.x*64;

  // ---- phase 1: gather-aggregate (wave w -> local rows w*16 .. w*16+15) ----
  {
    const int nbase = rbase0 + wave*16;
    int nn = nbase + (lane & 15);
    int2 sv = (nn < N) ? sd[nn] : make_int2(0, 0);
    const unsigned int* Xu = (const unsigned int*)Xin;
    for (int i = 0; i < 16; i++){
      int s0    = __builtin_amdgcn_readlane(sv.x, i);
      int dpack = __builtin_amdgcn_readlane(sv.y, i);
      int degp  = dpack & 0xffff;
      if (lane == 0) ldeg[wave*16 + i] = (float)(dpack >> 16);
      float acc0 = 0.f, acc1 = 0.f;
      for (int base = 0; base < degp; base += 64){
        int myidx = csr[s0 + base + lane];          // one coalesced load covers 64 edges
        int m = degp - base; m = (m < 64) ? m : 64; // multiple of 8
        for (int k = 0; k < m; k += 8){
          unsigned int v[8];
#pragma unroll
          for (int j = 0; j < 8; j++){
            int idx = __builtin_amdgcn_readlane(myidx, k + j);   // SGPR row index
            v[j] = Xu[(size_t)idx*64 + lane];
          }
#pragma unroll
          for (int j = 0; j < 8; j++){
            float2 f = __half22float2(*(__half2*)&v[j]);
            acc0 += f.x; acc1 += f.y;
          }
        }
      }
      __half2 ho = __floats2half2_rn(acc0, acc1);
      ((unsigned int*)&lg[wave*16 + i][0])[lane] = *(unsigned int*)&ho;
    }
  }
  __syncthreads();

  // ---- phase 2: MFMA GEMM. waves 0,1: cols 0-63; waves 2,3: cols 64-127 ----
  const int cthi = wave >> 1;
  half8 af[4][2];
#pragma unroll
  for (int kc = 0; kc < 4; kc++)
#pragma unroll
    for (int rt = 0; rt < 2; rt++){
      int rl = (wave & 1)*32 + rt*16 + l16;
      af[kc][rt] = *(const half8*)&lg[rl][kc*32 + quad*8];
    }
  __syncthreads();   // all lg reads done before out staging overwrites it

  floatx4 acc[2][4] = {};
#pragma unroll
  for (int kc = 0; kc < 4; kc++)
#pragma unroll
    for (int ct = 0; ct < 4; ct++){
      half8 bf = *(const half8*)(Wmain + (size_t)((cthi*4 + ct)*16 + l16)*128 + kc*32 + quad*8);
      acc[0][ct] = __builtin_amdgcn_mfma_f32_16x16x32_f16(af[kc][0], bf, acc[0][ct], 0, 0, 0);
      acc[1][ct] = __builtin_amdgcn_mfma_f32_16x16x32_f16(af[kc][1], bf, acc[1][ct], 0, 0, 0);
    }

  // ---- stage out to LDS (deg-scaled bias: reference sums (x W + b) over neighbors) ----
#pragma unroll
  for (int rt = 0; rt < 2; rt++){
    float dgv[4];
#pragma unroll
    for (int reg = 0; reg < 4; reg++)
      dgv[reg] = ldeg[(wave & 1)*32 + rt*16 + quad*4 + reg];
#pragma unroll
    for (int ct = 0; ct < 4; ct++){
      int col = (cthi*4 + ct)*16 + l16;
      float b = bias[col];
#pragma unroll
      for (int reg = 0; reg < 4; reg++){
        int rl = (wave & 1)*32 + rt*16 + quad*4 + reg;
        lg[rl][col] = (_Float16)(acc[rt][ct][reg] + b*dgv[reg]);
      }
    }
  }
  __syncthreads();

  // ---- phase 3a: coalesced global store (half8 chunks), zero row N for csr padding ----
#pragma unroll
  for (int i = 0; i < 4; i++){
    int idx8 = i*256 + tid;            // 1024 half8 chunks
    int row = idx8 >> 4, c8 = idx8 & 15;
    int gr = rbase0 + row;
    if (gr < N){
      *(half8*)(Out + (size_t)gr*128 + c8*8) = *(const half8*)&lg[row][c8*8];
    } else if (gr == N){
      half8 z = {};
      *(half8*)(Out + (size_t)gr*128 + c8*8) = z;
    }
  }

  // ---- phase 3b: head GEMM out_l @ Whd (wave w -> row-tile w) ----
  {
    floatx4 hacc = {};
#pragma unroll
    for (int kc = 0; kc < 4; kc++){
      half8 ha = *(const half8*)&lg[wave*16 + l16][kc*32 + quad*8];
      half8 bf = *(const half8*)(Whd + (size_t)l16*128 + kc*32 + quad*8);
      hacc = __builtin_amdgcn_mfma_f32_16x16x32_f16(ha, bf, hacc, 0, 0, 0);
    }
#pragma unroll
    for (int reg = 0; reg < 4; reg++)
      lheads[(wave*16 + quad*4 + reg)*16 + l16] = hacc[reg];
  }
  __syncthreads();

  // ---- phase 4: SE(3) epilogue for this layer ----
  if (tid < 64){
    int n = rbase0 + tid;
    if (n < N){
      float ds[13];
#pragma unroll
      for (int c = 0; c < 13; c++) ds[c] = lheads[tid*16 + c];
      se3_node_ds(n, ds, bc, bR, bt, pos_in, pos_o, R_o, t_o, layer);
    }
  }
}

// ---------------- layer-2 kernel: fused final GEMM z = out@Wf + bf (fp32) ---------------
__launch_bounds__(256)
__global__ void k_fused_fin(const _Float16* __restrict__ Xin,
                        const _Float16* __restrict__ Wmain,
                        const _Float16* __restrict__ Whd,
                        const float* __restrict__ bias,
                        const int* __restrict__ csr, const int2* __restrict__ sd,
                        int N, int layer,
                        const float* __restrict__ bc, const float* __restrict__ bR,
                        const float* __restrict__ bt, const float* __restrict__ pos_in,
                        float* __restrict__ pos_o, float* __restrict__ R_o,
                        float* __restrict__ t_o,
                        const _Float16* __restrict__ Wfin,
                        const float* __restrict__ bfin,
                        float* __restrict__ Zout){
  __shared__ __align__(16) _Float16 lg[64][136];
  __shared__ __align__(16) float lheads[64*16];
  __shared__ float ldeg[64];

  const int tid  = threadIdx.x;
  const int wave = tid >> 6;
  const int lane = tid & 63;
  const int quad = lane >> 4;
  const int l16  = lane & 15;
  const int rbase0 = blockIdx.x*64;

  // ---- phase 1: gather-aggregate ----
  {
    const int nbase = rbase0 + wave*16;
    int nn = nbase + (lane & 15);
    int2 sv = (nn < N) ? sd[nn] : make_int2(0, 0);
    const unsigned int* Xu = (const unsigned int*)Xin;
    for (int i = 0; i < 16; i++){
      int s0    = __builtin_amdgcn_readlane(sv.x, i);
      int dpack = __builtin_amdgcn_readlane(sv.y, i);
      int degp  = dpack & 0xffff;
      if (lane == 0) ldeg[wave*16 + i] = (float)(dpack >> 16);
      float acc0 = 0.f, acc1 = 0.f;
      for (int base = 0; base < degp; base += 64){
        int myidx = csr[s0 + base + lane];
        int m = degp - base; m = (m < 64) ? m : 64;
        for (int k = 0; k < m; k += 8){
          unsigned int v[8];
#pragma unroll
          for (int j = 0; j < 8; j++){
            int idx = __builtin_amdgcn_readlane(myidx, k + j);
            v[j] = Xu[(size_t)idx*64 + lane];
          }
#pragma unroll
          for (int j = 0; j < 8; j++){
            float2 f = __half22float2(*(__half2*)&v[j]);
            acc0 += f.x; acc1 += f.y;
          }
        }
      }
      __half2 ho = __floats2half2_rn(acc0, acc1);
      ((unsigned int*)&lg[wave*16 + i][0])[lane] = *(unsigned int*)&ho;
    }
  }
  __syncthreads();

  // ---- phase 2: MFMA GEMM ----
  const int cthi = wave >> 1;
  half8 af[4][2];
#pragma unroll
  for (int kc = 0; kc < 4; kc++)
#pragma unroll
    for (int rt = 0; rt < 2; rt++){
      int rl = (wave & 1)*32 + rt*16 + l16;
      af[kc][rt] = *(const half8*)&lg[rl][kc*32 + quad*8];
    }
  __syncthreads();

  floatx4 acc[2][4] = {};
#pragma unroll
  for (int kc = 0; kc < 4; kc++)
#pragma unroll
    for (int ct = 0; ct < 4; ct++){
      half8 bf = *(const half8*)(Wmain + (size_t)((cthi*4 + ct)*16 + l16)*128 + kc*32 + quad*8);
      acc[0][ct] = __builtin_amdgcn_mfma_f32_16x16x32_f16(af[kc][0], bf, acc[0][ct], 0, 0, 0);
      acc[1][ct] = __builtin_amdgcn_mfma_f32_16x16x32_f16(af[kc][1], bf, acc[1][ct], 0, 0, 0);
    }

#pragma unroll
  for (int rt = 0; rt < 2; rt++){
    float dgv[4];
#pragma unroll
    for (int reg = 0; reg < 4; reg++)
      dgv[reg] = ldeg[(wave & 1)*32 + rt*16 + quad*4 + reg];
#pragma unroll
    for (int ct = 0; ct < 4; ct++){
      int col = (cthi*4 + ct)*16 + l16;
      float b = bias[col];
#pragma unroll
      for (int reg = 0; reg < 4; reg++){
        int rl = (wave & 1)*32 + rt*16 + quad*4 + reg;
        lg[rl][col] = (_Float16)(acc[rt][ct][reg] + b*dgv[reg]);
      }
    }
  }
  __syncthreads();

  // ---- phase 3a': fused final GEMM  z = out @ Wf + bf, direct fp32 store ----
  {
    half8 zf[4][2];
#pragma unroll
    for (int kc = 0; kc < 4; kc++)
#pragma unroll
      for (int rt = 0; rt < 2; rt++){
        int rl = (wave & 1)*32 + rt*16 + l16;
        zf[kc][rt] = *(const half8*)&lg[rl][kc*32 + quad*8];
      }
    floatx4 zacc[2][4] = {};
#pragma unroll
    for (int kc = 0; kc < 4; kc++)
#pragma unroll
      for (int ct = 0; ct < 4; ct++){
        half8 bf = *(const half8*)(Wfin + (size_t)((cthi*4 + ct)*16 + l16)*128 + kc*32 + quad*8);
        zacc[0][ct] = __builtin_amdgcn_mfma_f32_16x16x32_f16(zf[kc][0], bf, zacc[0][ct], 0, 0, 0);
        zacc[1][ct] = __builtin_amdgcn_mfma_f32_16x16x32_f16(zf[kc][1], bf, zacc[1][ct], 0, 0, 0);
      }
#pragma unroll
    for (int rt = 0; rt < 2; rt++)
#pragma unroll
      for (int ct = 0; ct < 4; ct++){
        int col = (cthi*4 + ct)*16 + l16;
        float b = bfin[col];
#pragma unroll
        for (int reg = 0; reg < 4; reg++){
          int gr = rbase0 + (wave & 1)*32 + rt*16 + quad*4 + reg;
          if (gr < N) Zout[(size_t)gr*128 + col] = zacc[rt][ct][reg] + b;
        }
      }
  }

  // ---- phase 3b: head GEMM ----
  {
    floatx4 hacc = {};
#pragma unroll
    for (int kc = 0; kc < 4; kc++){
      half8 ha = *(const half8*)&lg[wave*16 + l16][kc*32 + quad*8];
      half8 bf = *(const half8*)(Whd + (size_t)l16*128 + kc*32 + quad*8);
      hacc = __builtin_amdgcn_mfma_f32_16x16x32_f16(ha, bf, hacc, 0, 0, 0);
    }
#pragma unroll
    for (int reg = 0; reg < 4; reg++)
      lheads[(wave*16 + quad*4 + reg)*16 + l16] = hacc[reg];
  }
  __syncthreads();

  // ---- phase 4: SE(3) epilogue ----
  if (tid < 64){
    int n = rbase0 + tid;
    if (n < N){
      float ds[13];
#pragma unroll
      for (int c = 0; c < 13; c++) ds[c] = lheads[tid*16 + c];
      se3_node_ds(n, ds, bc, bR, bt, pos_in, pos_o, R_o, t_o, layer);
    }
  }
}

extern "C" void kernel_launch(void* const* d_in, const int* in_sizes, int n_in,
                              void* d_out, int out_size, void* d_ws, size_t ws_size,
                              hipStream_t stream){
  const float* x0  = (const float*)d_in[0];
  const float* pos = (const float*)d_in[1];
  const int*   ei  = (const int*)d_in[2];
  const float* Wl  = (const float*)d_in[3];
  const float* bl  = (const float*)d_in[4];
  const float* Wc  = (const float*)d_in[5];
  const float* bc  = (const float*)d_in[6];
  const float* WR  = (const float*)d_in[7];
  const float* bR  = (const float*)d_in[8];
  const float* Wt  = (const float*)d_in[9];
  const float* bt  = (const float*)d_in[10];
  const float* Wf  = (const float*)d_in[11];
  const float* bf  = (const float*)d_in[12];

  const int N = in_sizes[0] / 128;
  const int E = in_sizes[2] / 2;
  const int* srcp = ei;
  const int* dstp = ei + E;

  float* z_out = (float*)d_out;
  float* pos_o = z_out + (size_t)N*128;
  float* R_o   = pos_o + (size_t)N*3;
  float* t_o   = R_o   + (size_t)N*9;

  const int nbuck = (N + BN - 1) >> BSH;                       // 128-node buckets
  const int capB  = (((E + nbuck - 1)/nbuck)*5/4 + 256 + 63) & ~63;
  const int capC  = capB + BN*7;

  char* ws = (char*)d_ws;
  size_t off = 0;
  auto alloc = [&](size_t bytes)->char*{
    char* p = ws + off; off += (bytes + 511) & ~(size_t)511; return p;
  };
  _Float16* bufA = (_Float16*)alloc((size_t)(N+1)*128*2);   // x16 / out1
  _Float16* bufB = (_Float16*)alloc((size_t)(N+1)*128*2);   // out0 (out2 never stored)
  _Float16* wTx  = (_Float16*)alloc((size_t)4*128*128*2);
  _Float16* wHd  = (_Float16*)alloc((size_t)3*16*128*2);
  int2*  sd     = (int2*) alloc((size_t)N*8);
  int*   cursor = (int*)  alloc((size_t)nbuck*4);
  int*   binned = (int*)  alloc((size_t)nbuck*capB*4);
  int*   csr    = (int*)  alloc((size_t)nbuck*capC*4);

  const int cvtB = ((N+1)*16 + 255)/256;
  const int prep_total = 4*128*128 + 3*16*128;
  const int prepB = (prep_total + 255)/256;
  const int binB  = (E + 4095)/4096;

  hipMemsetAsync(cursor, 0, (size_t)nbuck*4, stream);
  k_prebin<<<dim3(cvtB + prepB + binB), dim3(256), 0, stream>>>(
      x0, bufA, N, Wl, Wf, Wc, WR, Wt, wTx, wHd,
      srcp, dstp, E, nbuck, capB, cursor, binned, cvtB, prepB);
  k_build<<<dim3(nbuck), dim3(256), 0, stream>>>(binned, cursor, N, capB, capC, sd, csr);

  const int fused_blocks = (N + 64) >> 6;   // 64 rows/block; covers zero-pad row N

  // layer 0: bufA -> bufB
  k_fused<<<dim3(fused_blocks), dim3(256), 0, stream>>>(
      bufA, wTx, wHd, bl,
      csr, sd, bufB, N, 0,
      bc, bR, bt, pos, pos_o, R_o, t_o);
  // layer 1: bufB -> bufA
  k_fused<<<dim3(fused_blocks), dim3(256), 0, stream>>>(
      bufB, wTx + (size_t)16384, wHd + (size_t)2048, bl + 128,
      csr, sd, bufA, N, 1,
      bc + 1, bR + 9, bt + 3, pos, pos_o, R_o, t_o);
  // layer 2 (+ fused final GEMM): bufA -> z
  k_fused_fin<<<dim3(fused_blocks), dim3(256), 0, stream>>>(
      bufA, wTx + (size_t)2*16384, wHd + (size_t)2*2048, bl + 256,
      csr, sd, N, 2,
      bc + 2, bR + 18, bt + 6, pos, pos_o, R_o, t_o,
      wTx + (size_t)3*16384, bf, z_out);
}